// Round 1
// baseline (1487.961 us; speedup 1.0000x reference)
//
#include <hip/hip_runtime.h>
#include <cstddef>

// Problem constants
#define NB   1024
#define CIN  384
#define NPIX 361      // 19*19
#define OPST 364      // padded pixel stride for outp workspace (364*4B % 16 == 0 -> aligned float4 rows)
#define CP   48       // p channels
#define CG   48       // g channels
#define NCH  96       // CP + CG
#define TILE 128      // pixels per block in K1
#define KC   32       // k-chunk (halved vs prev: 29.2KB LDS -> 5 blocks/CU)
#define WSTR 100      // padded LDS stride for W chunk [KC][96] (400B rows: 16B-aligned, 4-way max on stage write)

// LDS plan (floats): xs[0..4096) = x chunk [KC][TILE]; wl[4096..7296) = W chunk [KC][WSTR]
#define XS_F   (KC * TILE)          // 4096
#define SMEM_F (XS_F + KC * WSTR)   // 7296 floats = 29184 B

__global__ __launch_bounds__(256, 5) void k1_conv1_pool(
    const float* __restrict__ x, const float* __restrict__ mask,
    const float* __restrict__ w1p, const float* __restrict__ w1g,
    const float* __restrict__ betag,
    float* __restrict__ outp, float* __restrict__ psum, float* __restrict__ pmax)
{
    __shared__ float smem[SMEM_F];
    float* xs = smem;
    float* wl = smem + XS_F;

    const int n  = blockIdx.x;
    const int t  = blockIdx.y;          // 0..2, pixel tile
    const int l0 = t * TILE;
    const int tid = threadIdx.x;
    const int pg  = tid & 31;           // pixel group: pixels l0 + pg*4 + 0..3
    const int cg  = tid >> 5;           // 0..7: ch = cg*12 + j ; cg<4 -> p ch, cg>=4 -> g ch

    float acc[12][4];
    #pragma unroll
    for (int j = 0; j < 12; ++j)
        #pragma unroll
        for (int k = 0; k < 4; ++k) acc[j][k] = 0.f;

    const float* xn = x + (size_t)n * CIN * NPIX;
    const int xoff = pg * 4;            // float index into xs row (16B aligned)
    const int woff = cg * 12;           // float index into wl row (48B: 16B aligned)

    for (int ck = 0; ck < CIN; ck += KC) {
        // stage x chunk [KC][TILE], coalesced over pixels
        #pragma unroll
        for (int i = 0; i < (KC * TILE / 256); ++i) {     // 16
            int e = tid + 256 * i;
            int c = e >> 7;            // 0..31
            int p = e & 127;
            int gp = l0 + p;
            xs[c * TILE + p] = (gp < NPIX) ? xn[(size_t)(ck + c) * NPIX + gp] : 0.f;
        }
        // stage W chunk: global coalesced along c (32 consecutive), LDS layout wl[c][ch]
        #pragma unroll
        for (int i = 0; i < (KC * NCH / 256); ++i) {      // 12
            int e = tid + 256 * i;
            int ch = e >> 5;           // 0..95
            int c  = e & 31;
            float v = (ch < CP) ? w1p[ch * CIN + ck + c]
                                : w1g[(ch - CP) * CIN + ck + c];
            wl[c * WSTR + ch] = v;
        }
        __syncthreads();

        #pragma unroll 2
        for (int c = 0; c < KC; ++c) {
            float4 xv = *reinterpret_cast<const float4*>(xs + c * TILE + xoff);
            const float4* wp = reinterpret_cast<const float4*>(wl + c * WSTR + woff);
            float4 wA = wp[0];
            float4 wB = wp[1];
            float4 wC = wp[2];
#define FMA4(J, WW) \
            acc[J][0] += (WW) * xv.x; acc[J][1] += (WW) * xv.y; \
            acc[J][2] += (WW) * xv.z; acc[J][3] += (WW) * xv.w;
            FMA4(0,  wA.x) FMA4(1,  wA.y) FMA4(2,  wA.z) FMA4(3,  wA.w)
            FMA4(4,  wB.x) FMA4(5,  wB.y) FMA4(6,  wB.z) FMA4(7,  wB.w)
            FMA4(8,  wC.x) FMA4(9,  wC.y) FMA4(10, wC.z) FMA4(11, wC.w)
#undef FMA4
        }
        __syncthreads();
    }

    const int pbase = l0 + pg * 4;

    if (cg < 4) {
        // p channels: store pre-activation to padded workspace, aligned float4 rows.
        // pbase is a multiple of 4; padding pixels 361..363 may be written (harmless).
        if (pbase < OPST) {
            float* op = outp + ((size_t)n * CP + cg * 12) * OPST + pbase;
            #pragma unroll
            for (int j = 0; j < 12; ++j) {
                *reinterpret_cast<float4*>(op + (size_t)j * OPST) =
                    make_float4(acc[j][0], acc[j][1], acc[j][2], acc[j][3]);
            }
        }
    } else {
        // g channels: relu((acc+beta)*mask); per-thread partial sum/max over 4 pixels,
        // then shuffle-butterfly over the 32 pixel groups (lanes 0..31 / 32..63 halves).
        const float* mn = mask + (size_t)n * NPIX;
        float m[4];
        #pragma unroll
        for (int k = 0; k < 4; ++k) m[k] = (pbase + k < NPIX) ? mn[pbase + k] : 0.f;

        float s[12], mx[12];
        #pragma unroll
        for (int j = 0; j < 12; ++j) {
            float b = betag[(cg - 4) * 12 + j];
            float ssum = 0.f;
            float smax = -1e30f;
            #pragma unroll
            for (int k = 0; k < 4; ++k) {
                bool ok = (pbase + k) < NPIX;
                float r = fmaxf((acc[j][k] + b) * m[k], 0.f);
                ssum += ok ? r : 0.f;
                smax = fmaxf(smax, ok ? (r + (m[k] - 1.f)) : -1e30f);
            }
            s[j] = ssum;
            mx[j] = smax;
        }
        // butterfly over pixel groups: xor masks 16,8,4,2,1 stay within each 32-lane half
        #pragma unroll
        for (int sh = 16; sh >= 1; sh >>= 1) {
            #pragma unroll
            for (int j = 0; j < 12; ++j) {
                s[j]  += __shfl_xor(s[j], sh);
                mx[j]  = fmaxf(mx[j], __shfl_xor(mx[j], sh));
            }
        }
        if (pg == 0) {
            float* ps = psum + ((size_t)n * 3 + t) * CG + (cg - 4) * 12;
            float* pm = pmax + ((size_t)n * 3 + t) * CG + (cg - 4) * 12;
            #pragma unroll
            for (int j = 0; j < 12; ++j) { ps[j] = s[j]; pm[j] = mx[j]; }
        }
    }
}

__global__ __launch_bounds__(64) void k2_pool_linears(
    const float* __restrict__ psum, const float* __restrict__ pmax,
    const float* __restrict__ mask_sum,
    const float* __restrict__ wlg, const float* __restrict__ wlp,
    const float* __restrict__ blp, const float* __restrict__ wlp2,
    const float* __restrict__ beta2,
    float* __restrict__ glin, float* __restrict__ out)
{
    __shared__ float gp[3 * CG];
    __shared__ float hbuf[CP];
    const int n = blockIdx.x;
    const int tid = threadIdx.x;

    if (tid < CG) {
        float s  = psum[((size_t)n*3 + 0)*CG + tid] + psum[((size_t)n*3 + 1)*CG + tid]
                 + psum[((size_t)n*3 + 2)*CG + tid];
        float mx = fmaxf(fmaxf(pmax[((size_t)n*3 + 0)*CG + tid],
                               pmax[((size_t)n*3 + 1)*CG + tid]),
                               pmax[((size_t)n*3 + 2)*CG + tid]);
        float ms = mask_sum[n];
        float mean = s / ms;
        float offset = sqrtf(ms) - 14.0f;
        gp[tid]        = mean;
        gp[CG + tid]   = mean * (offset * 0.1f);
        gp[2*CG + tid] = mx;
    }
    __syncthreads();
    if (tid < CP) {
        float h = blp[tid];
        float gl = 0.f;
        #pragma unroll 4
        for (int k = 0; k < 3*CG; ++k) {
            float g = gp[k];
            h  += g * wlp[tid * (3*CG) + k];
            gl += g * wlg[tid * (3*CG) + k];
        }
        h = fmaxf(h, 0.f);
        hbuf[tid] = h;
        glin[(size_t)n * CP + tid] = gl + beta2[tid];   // fold beta2 here, k3 skips it
    }
    __syncthreads();
    if (tid < 2) {
        float o = 0.f;
        #pragma unroll
        for (int j = 0; j < CP; ++j) o += hbuf[j] * wlp2[tid * CP + j];
        out[((size_t)n * 6 + (tid ? 5 : 0)) * 362 + 361] = o;
    }
}

// 4 pixels per thread, aligned float4 reads of the padded outp workspace.
// grid = 1024*91/256 = 364 blocks exactly.
__global__ __launch_bounds__(256) void k3_epilogue(
    const float* __restrict__ outp, const float* __restrict__ glin,
    const float* __restrict__ mask,
    const float* __restrict__ w2, float* __restrict__ out)
{
    int gid = blockIdx.x * 256 + threadIdx.x;   // 0 .. 93183
    int n = gid / 91;
    int q = gid - n * 91;
    int p0 = q * 4;

    const float* mn = mask + (size_t)n * NPIX;
    float m[4];
    #pragma unroll
    for (int k = 0; k < 4; ++k) m[k] = (p0 + k < NPIX) ? mn[p0 + k] : 0.f;

    const float* op = outp + (size_t)n * CP * OPST + p0;
    const float* gl = glin + (size_t)n * CP;

    float o0[4] = {0.f, 0.f, 0.f, 0.f};
    float o1[4] = {0.f, 0.f, 0.f, 0.f};
    #pragma unroll 4
    for (int c = 0; c < CP; ++c) {
        float4 o = *reinterpret_cast<const float4*>(op + (size_t)c * OPST);
        float g  = gl[c];                 // beta2 already folded in
        float wa = w2[c];
        float wb = w2[CP + c];
        float v0 = fmaxf((o.x + g) * m[0], 0.f);
        float v1 = fmaxf((o.y + g) * m[1], 0.f);
        float v2 = fmaxf((o.z + g) * m[2], 0.f);
        float v3 = fmaxf((o.w + g) * m[3], 0.f);
        o0[0] += wa * v0; o0[1] += wa * v1; o0[2] += wa * v2; o0[3] += wa * v3;
        o1[0] += wb * v0; o1[1] += wb * v1; o1[2] += wb * v2; o1[3] += wb * v3;
    }
    float* outr0 = out + ((size_t)n * 6 + 0) * 362;
    float* outr5 = out + ((size_t)n * 6 + 5) * 362;
    #pragma unroll
    for (int k = 0; k < 4; ++k) {
        if (p0 + k < NPIX) {
            float pen = (1.f - m[k]) * 5000.f;
            outr0[p0 + k] = o0[k] - pen;
            outr5[p0 + k] = o1[k] - pen;
        }
    }
}

extern "C" void kernel_launch(void* const* d_in, const int* in_sizes, int n_in,
                              void* d_out, int out_size, void* d_ws, size_t ws_size,
                              hipStream_t stream) {
    const float* x     = (const float*)d_in[0];
    const float* mask  = (const float*)d_in[1];
    const float* msum  = (const float*)d_in[2];
    const float* w1p   = (const float*)d_in[3];
    const float* w1g   = (const float*)d_in[4];
    const float* betag = (const float*)d_in[5];
    const float* wlg   = (const float*)d_in[6];
    const float* wlp   = (const float*)d_in[7];
    const float* blp   = (const float*)d_in[8];
    const float* wlp2  = (const float*)d_in[9];
    const float* beta2 = (const float*)d_in[10];
    const float* w2    = (const float*)d_in[11];
    float* out = (float*)d_out;

    float* ws     = (float*)d_ws;
    float* wsOutp = ws;                                     // 1024*48*364 (padded rows)
    float* psum   = ws + (size_t)NB * CP * OPST;            // 1024*3*48
    float* pmax   = psum + (size_t)NB * 3 * CG;             // 1024*3*48
    float* glin   = pmax + (size_t)NB * 3 * CG;             // 1024*48

    // channels 1..4 (and all untouched slots) must be zero; harness re-poisons d_out
    hipMemsetAsync(d_out, 0, (size_t)NB * 6 * 362 * sizeof(float), stream);

    dim3 g1(NB, 3);
    k1_conv1_pool<<<g1, 256, 0, stream>>>(x, mask, w1p, w1g, betag, wsOutp, psum, pmax);
    k2_pool_linears<<<NB, 64, 0, stream>>>(psum, pmax, msum, wlg, wlp, blp, wlp2, beta2, glin, out);
    k3_epilogue<<<(NB * 91) / 256, 256, 0, stream>>>(wsOutp, glin, mask, w2, out);
}

// Round 2
// 1077.413 us; speedup vs baseline: 1.3810x; 1.3810x over previous
//
#include <hip/hip_runtime.h>
#include <cstddef>

// Problem constants
#define NB   1024
#define CIN  384
#define NPIX 361      // 19*19
#define OPST 364      // padded pixel stride for outp workspace (364*4B % 16 == 0 -> aligned float4 rows)
#define CP   48       // p channels
#define CG   48       // g channels
#define NCH  96       // CP + CG
#define TILE 128      // pixels per block in K1
#define KC   32       // k-chunk (29.2KB LDS)
#define WSTR 100      // padded LDS stride for W chunk [KC][96] (400B rows: 16B-aligned)

// LDS plan (floats): xs[0..4096) = x chunk [KC][TILE]; wl[4096..7296) = W chunk [KC][WSTR]
#define XS_F   (KC * TILE)          // 4096
#define SMEM_F (XS_F + KC * WSTR)   // 7296 floats = 29184 B

// launch_bounds(256, 4): VGPR cap 128 -> the ~85-reg working set (48 acc + frags + addr)
// fits WITHOUT spilling. (256,5) forced <=64 VGPRs (occupancy steps at 64/128/256) and
// spilled the accumulator tile to scratch: FETCH +524MB, WRITE +153MB, VALUBusy 29%.
__global__ __launch_bounds__(256, 4) void k1_conv1_pool(
    const float* __restrict__ x, const float* __restrict__ mask,
    const float* __restrict__ w1p, const float* __restrict__ w1g,
    const float* __restrict__ betag,
    float* __restrict__ outp, float* __restrict__ psum, float* __restrict__ pmax)
{
    __shared__ float smem[SMEM_F];
    float* xs = smem;
    float* wl = smem + XS_F;

    const int n  = blockIdx.x;
    const int t  = blockIdx.y;          // 0..2, pixel tile
    const int l0 = t * TILE;
    const int tid = threadIdx.x;
    const int pg  = tid & 31;           // pixel group: pixels l0 + pg*4 + 0..3
    const int cg  = tid >> 5;           // 0..7: ch = cg*12 + j ; cg<4 -> p ch, cg>=4 -> g ch

    float acc[12][4];
    #pragma unroll
    for (int j = 0; j < 12; ++j)
        #pragma unroll
        for (int k = 0; k < 4; ++k) acc[j][k] = 0.f;

    const float* xn = x + (size_t)n * CIN * NPIX;
    const int xoff = pg * 4;            // float index into xs row (16B aligned)
    const int woff = cg * 12;           // float index into wl row (48B: 16B aligned)

    for (int ck = 0; ck < CIN; ck += KC) {
        // stage x chunk [KC][TILE], coalesced over pixels
        #pragma unroll
        for (int i = 0; i < (KC * TILE / 256); ++i) {     // 16
            int e = tid + 256 * i;
            int c = e >> 7;            // 0..31
            int p = e & 127;
            int gp = l0 + p;
            xs[c * TILE + p] = (gp < NPIX) ? xn[(size_t)(ck + c) * NPIX + gp] : 0.f;
        }
        // stage W chunk: global coalesced along c (32 consecutive), LDS layout wl[c][ch]
        #pragma unroll
        for (int i = 0; i < (KC * NCH / 256); ++i) {      // 12
            int e = tid + 256 * i;
            int ch = e >> 5;           // 0..95
            int c  = e & 31;
            float v = (ch < CP) ? w1p[ch * CIN + ck + c]
                                : w1g[(ch - CP) * CIN + ck + c];
            wl[c * WSTR + ch] = v;
        }
        __syncthreads();

        #pragma unroll 2
        for (int c = 0; c < KC; ++c) {
            float4 xv = *reinterpret_cast<const float4*>(xs + c * TILE + xoff);
            const float4* wp = reinterpret_cast<const float4*>(wl + c * WSTR + woff);
            float4 wA = wp[0];
            float4 wB = wp[1];
            float4 wC = wp[2];
#define FMA4(J, WW) \
            acc[J][0] += (WW) * xv.x; acc[J][1] += (WW) * xv.y; \
            acc[J][2] += (WW) * xv.z; acc[J][3] += (WW) * xv.w;
            FMA4(0,  wA.x) FMA4(1,  wA.y) FMA4(2,  wA.z) FMA4(3,  wA.w)
            FMA4(4,  wB.x) FMA4(5,  wB.y) FMA4(6,  wB.z) FMA4(7,  wB.w)
            FMA4(8,  wC.x) FMA4(9,  wC.y) FMA4(10, wC.z) FMA4(11, wC.w)
#undef FMA4
        }
        __syncthreads();
    }

    const int pbase = l0 + pg * 4;

    if (cg < 4) {
        // p channels: store pre-activation to padded workspace, aligned float4 rows.
        // pbase is a multiple of 4; padding pixels 361..363 may be written (harmless).
        if (pbase < OPST) {
            float* op = outp + ((size_t)n * CP + cg * 12) * OPST + pbase;
            #pragma unroll
            for (int j = 0; j < 12; ++j) {
                *reinterpret_cast<float4*>(op + (size_t)j * OPST) =
                    make_float4(acc[j][0], acc[j][1], acc[j][2], acc[j][3]);
            }
        }
    } else {
        // g channels: relu((acc+beta)*mask); per-thread partial sum/max over 4 pixels,
        // then shuffle-butterfly over the 32 pixel groups (lanes 0..31 / 32..63 halves).
        const float* mn = mask + (size_t)n * NPIX;
        float m[4];
        #pragma unroll
        for (int k = 0; k < 4; ++k) m[k] = (pbase + k < NPIX) ? mn[pbase + k] : 0.f;

        float s[12], mx[12];
        #pragma unroll
        for (int j = 0; j < 12; ++j) {
            float b = betag[(cg - 4) * 12 + j];
            float ssum = 0.f;
            float smax = -1e30f;
            #pragma unroll
            for (int k = 0; k < 4; ++k) {
                bool ok = (pbase + k) < NPIX;
                float r = fmaxf((acc[j][k] + b) * m[k], 0.f);
                ssum += ok ? r : 0.f;
                smax = fmaxf(smax, ok ? (r + (m[k] - 1.f)) : -1e30f);
            }
            s[j] = ssum;
            mx[j] = smax;
        }
        // butterfly over pixel groups: xor masks 16,8,4,2,1 stay within each 32-lane half
        #pragma unroll
        for (int sh = 16; sh >= 1; sh >>= 1) {
            #pragma unroll
            for (int j = 0; j < 12; ++j) {
                s[j]  += __shfl_xor(s[j], sh);
                mx[j]  = fmaxf(mx[j], __shfl_xor(mx[j], sh));
            }
        }
        if (pg == 0) {
            float* ps = psum + ((size_t)n * 3 + t) * CG + (cg - 4) * 12;
            float* pm = pmax + ((size_t)n * 3 + t) * CG + (cg - 4) * 12;
            #pragma unroll
            for (int j = 0; j < 12; ++j) { ps[j] = s[j]; pm[j] = mx[j]; }
        }
    }
}

__global__ __launch_bounds__(64) void k2_pool_linears(
    const float* __restrict__ psum, const float* __restrict__ pmax,
    const float* __restrict__ mask_sum,
    const float* __restrict__ wlg, const float* __restrict__ wlp,
    const float* __restrict__ blp, const float* __restrict__ wlp2,
    const float* __restrict__ beta2,
    float* __restrict__ glin, float* __restrict__ out)
{
    __shared__ float gp[3 * CG];
    __shared__ float hbuf[CP];
    const int n = blockIdx.x;
    const int tid = threadIdx.x;

    if (tid < CG) {
        float s  = psum[((size_t)n*3 + 0)*CG + tid] + psum[((size_t)n*3 + 1)*CG + tid]
                 + psum[((size_t)n*3 + 2)*CG + tid];
        float mx = fmaxf(fmaxf(pmax[((size_t)n*3 + 0)*CG + tid],
                               pmax[((size_t)n*3 + 1)*CG + tid]),
                               pmax[((size_t)n*3 + 2)*CG + tid]);
        float ms = mask_sum[n];
        float mean = s / ms;
        float offset = sqrtf(ms) - 14.0f;
        gp[tid]        = mean;
        gp[CG + tid]   = mean * (offset * 0.1f);
        gp[2*CG + tid] = mx;
    }
    __syncthreads();
    if (tid < CP) {
        float h = blp[tid];
        float gl = 0.f;
        #pragma unroll 4
        for (int k = 0; k < 3*CG; ++k) {
            float g = gp[k];
            h  += g * wlp[tid * (3*CG) + k];
            gl += g * wlg[tid * (3*CG) + k];
        }
        h = fmaxf(h, 0.f);
        hbuf[tid] = h;
        glin[(size_t)n * CP + tid] = gl + beta2[tid];   // fold beta2 here, k3 skips it
    }
    __syncthreads();
    if (tid < 2) {
        float o = 0.f;
        #pragma unroll
        for (int j = 0; j < CP; ++j) o += hbuf[j] * wlp2[tid * CP + j];
        out[((size_t)n * 6 + (tid ? 5 : 0)) * 362 + 361] = o;
    }
}

// 4 pixels per thread, aligned float4 reads of the padded outp workspace.
// grid = 1024*91/256 = 364 blocks exactly.
__global__ __launch_bounds__(256) void k3_epilogue(
    const float* __restrict__ outp, const float* __restrict__ glin,
    const float* __restrict__ mask,
    const float* __restrict__ w2, float* __restrict__ out)
{
    int gid = blockIdx.x * 256 + threadIdx.x;   // 0 .. 93183
    int n = gid / 91;
    int q = gid - n * 91;
    int p0 = q * 4;

    const float* mn = mask + (size_t)n * NPIX;
    float m[4];
    #pragma unroll
    for (int k = 0; k < 4; ++k) m[k] = (p0 + k < NPIX) ? mn[p0 + k] : 0.f;

    const float* op = outp + (size_t)n * CP * OPST + p0;
    const float* gl = glin + (size_t)n * CP;

    float o0[4] = {0.f, 0.f, 0.f, 0.f};
    float o1[4] = {0.f, 0.f, 0.f, 0.f};
    #pragma unroll 4
    for (int c = 0; c < CP; ++c) {
        float4 o = *reinterpret_cast<const float4*>(op + (size_t)c * OPST);
        float g  = gl[c];                 // beta2 already folded in
        float wa = w2[c];
        float wb = w2[CP + c];
        float v0 = fmaxf((o.x + g) * m[0], 0.f);
        float v1 = fmaxf((o.y + g) * m[1], 0.f);
        float v2 = fmaxf((o.z + g) * m[2], 0.f);
        float v3 = fmaxf((o.w + g) * m[3], 0.f);
        o0[0] += wa * v0; o0[1] += wa * v1; o0[2] += wa * v2; o0[3] += wa * v3;
        o1[0] += wb * v0; o1[1] += wb * v1; o1[2] += wb * v2; o1[3] += wb * v3;
    }
    float* outr0 = out + ((size_t)n * 6 + 0) * 362;
    float* outr5 = out + ((size_t)n * 6 + 5) * 362;
    #pragma unroll
    for (int k = 0; k < 4; ++k) {
        if (p0 + k < NPIX) {
            float pen = (1.f - m[k]) * 5000.f;
            outr0[p0 + k] = o0[k] - pen;
            outr5[p0 + k] = o1[k] - pen;
        }
    }
}

extern "C" void kernel_launch(void* const* d_in, const int* in_sizes, int n_in,
                              void* d_out, int out_size, void* d_ws, size_t ws_size,
                              hipStream_t stream) {
    const float* x     = (const float*)d_in[0];
    const float* mask  = (const float*)d_in[1];
    const float* msum  = (const float*)d_in[2];
    const float* w1p   = (const float*)d_in[3];
    const float* w1g   = (const float*)d_in[4];
    const float* betag = (const float*)d_in[5];
    const float* wlg   = (const float*)d_in[6];
    const float* wlp   = (const float*)d_in[7];
    const float* blp   = (const float*)d_in[8];
    const float* wlp2  = (const float*)d_in[9];
    const float* beta2 = (const float*)d_in[10];
    const float* w2    = (const float*)d_in[11];
    float* out = (float*)d_out;

    float* ws     = (float*)d_ws;
    float* wsOutp = ws;                                     // 1024*48*364 (padded rows)
    float* psum   = ws + (size_t)NB * CP * OPST;            // 1024*3*48
    float* pmax   = psum + (size_t)NB * 3 * CG;             // 1024*3*48
    float* glin   = pmax + (size_t)NB * 3 * CG;             // 1024*48

    // channels 1..4 (and all untouched slots) must be zero; harness re-poisons d_out
    hipMemsetAsync(d_out, 0, (size_t)NB * 6 * 362 * sizeof(float), stream);

    dim3 g1(NB, 3);
    k1_conv1_pool<<<g1, 256, 0, stream>>>(x, mask, w1p, w1g, betag, wsOutp, psum, pmax);
    k2_pool_linears<<<NB, 64, 0, stream>>>(psum, pmax, msum, wlg, wlp, blp, wlp2, beta2, glin, out);
    k3_epilogue<<<(NB * 91) / 256, 256, 0, stream>>>(wsOutp, glin, mask, w2, out);
}